// Round 1
// baseline (89234.424 us; speedup 1.0000x reference)
//
#include <hip/hip_runtime.h>
#include <stdint.h>
#include <math.h>

namespace {

constexpr int B = 256, L = 256, F = 38, H = 512, D = 512, Z = 16, NF = 20;
constexpr float LOG2PI_F = 1.8378770664093453f;
constexpr int LBZ = L * B * Z;      // 1048576
constexpr int HALF = LBZ / 2;       // 524288

// ---------------- math helpers ----------------

__device__ __forceinline__ float sigmoidf_(float x) {
  return 1.0f / (1.0f + expf(-x));
}
__device__ __forceinline__ float softplusf_(float x) {
  return fmaxf(x, 0.0f) + log1pf(expf(-fabsf(x)));
}

__device__ __forceinline__ void waveReduceAtomicAdd(float* dst, float v, int tid) {
  #pragma unroll
  for (int off = 32; off > 0; off >>= 1) v += __shfl_down(v, off, 64);
  if ((tid & 63) == 0) atomicAdd(dst, v);
}

// ---------------- threefry2x32 (JAX-compatible) ----------------

__host__ __device__ inline uint32_t rotl32_(uint32_t x, int d) {
  return (x << d) | (x >> (32 - d));
}

__host__ __device__ inline void threefry2x32_(uint32_t k0, uint32_t k1,
                                              uint32_t x0, uint32_t x1,
                                              uint32_t& o0, uint32_t& o1) {
  const uint32_t ks2 = k0 ^ k1 ^ 0x1BD11BDAu;
  uint32_t v0 = x0 + k0;
  uint32_t v1 = x1 + k1;
#define TF_RND(r) { v0 += v1; v1 = rotl32_(v1, r); v1 ^= v0; }
  TF_RND(13) TF_RND(15) TF_RND(26) TF_RND(6)
  v0 += k1;  v1 += ks2 + 1u;
  TF_RND(17) TF_RND(29) TF_RND(16) TF_RND(24)
  v0 += ks2; v1 += k0 + 2u;
  TF_RND(13) TF_RND(15) TF_RND(26) TF_RND(6)
  v0 += k0;  v1 += k1 + 3u;
  TF_RND(17) TF_RND(29) TF_RND(16) TF_RND(24)
  v0 += k1;  v1 += ks2 + 4u;
  TF_RND(13) TF_RND(15) TF_RND(26) TF_RND(6)
  v0 += ks2; v1 += k0 + 5u;
#undef TF_RND
  o0 = v0; o1 = v1;
}

// XLA f32 erf_inv (Giles polynomial) — matches jax.random.normal path
__device__ __forceinline__ float erfinv_f_(float x) {
  float w = -log1pf(-x * x);
  float p;
  if (w < 5.0f) {
    w -= 2.5f;
    p = 2.81022636e-08f;
    p = fmaf(p, w, 3.43273939e-07f);
    p = fmaf(p, w, -3.5233877e-06f);
    p = fmaf(p, w, -4.39150654e-06f);
    p = fmaf(p, w, 0.00021858087f);
    p = fmaf(p, w, -0.00125372503f);
    p = fmaf(p, w, -0.00417768164f);
    p = fmaf(p, w, 0.246640727f);
    p = fmaf(p, w, 1.50140941f);
  } else {
    w = sqrtf(w) - 3.0f;
    p = -0.000200214257f;
    p = fmaf(p, w, 0.000100950558f);
    p = fmaf(p, w, 0.00134934322f);
    p = fmaf(p, w, -0.00367342844f);
    p = fmaf(p, w, 0.00573950773f);
    p = fmaf(p, w, -0.0076224613f);
    p = fmaf(p, w, 0.00943887047f);
    p = fmaf(p, w, 1.00167406f);
    p = fmaf(p, w, 2.83297682f);
  }
  return p * x;
}

__device__ __forceinline__ float bits_to_normal_(uint32_t bits) {
  uint32_t m = (bits >> 9) | 0x3f800000u;
  float f = __uint_as_float(m) - 1.0f;          // [0, 1)
  float u = f * 2.0f + (-0.99999994f);          // JAX scale rounds to exactly 2.0f
  u = fmaxf(-0.99999994f, u);
  return 1.41421356f * erfinv_f_(u);
}

// ---------------- kernels ----------------

__global__ __launch_bounds__(256) void k_transpose_x(const float* __restrict__ x,
                                                     float* __restrict__ xT) {
  int idx = blockIdx.x * blockDim.x + threadIdx.x;  // over B*L*F
  int f = idx % F;
  int t = (idx / F) % L;
  int b = idx / (F * L);
  xT[(t * F + f) * B + b] = x[idx];
}

// eps_z stored; eps_p square-sum folded straight into kld accumulator.
__global__ __launch_bounds__(256) void k_noise(float* __restrict__ eps_z,
                                               float* __restrict__ kld_acc,
                                               uint32_t kz0, uint32_t kz1,
                                               uint32_t kp0, uint32_t kp1) {
  int i = blockIdx.x * blockDim.x + threadIdx.x;  // [0, HALF)
  uint32_t a0, a1, b0, b1;
  threefry2x32_(kz0, kz1, (uint32_t)i, (uint32_t)(i + HALF), a0, a1);
  float ez0 = bits_to_normal_(a0);
  float ez1 = bits_to_normal_(a1);
  eps_z[i] = ez0;
  eps_z[i + HALF] = ez1;
  threefry2x32_(kp0, kp1, (uint32_t)i, (uint32_t)(i + HALF), b0, b1);
  float ep0 = bits_to_normal_(b0);
  float ep1 = bits_to_normal_(b1);
  float local = -0.5f * (ez0 * ez0 + ez1 * ez1) + 0.5f * (ep0 * ep0 + ep1 * ep1);
  waveReduceAtomicAdd(kld_acc, local, threadIdx.x);
}

// GRU cell: inputs feature-major [in_dim][B], hidden [H][B]; 2 outputs per block.
__global__ __launch_bounds__(256) void k_gru(const float* __restrict__ inT, int in_dim,
                                             const float* __restrict__ hT,
                                             const float* __restrict__ Wih,
                                             const float* __restrict__ Whh,
                                             const float* __restrict__ bih,
                                             const float* __restrict__ bhh,
                                             float* __restrict__ h_outT) {
  const int b = threadIdx.x;
  const int j = blockIdx.x * 2;
  float ir0 = bih[j],     iz0 = bih[j + H],     in0 = bih[j + 2 * H];
  float ir1 = bih[j + 1], iz1 = bih[j + 1 + H], in1 = bih[j + 1 + 2 * H];
  for (int f = 0; f < in_dim; ++f) {
    float v = inT[f * B + b];
    ir0 = fmaf(Wih[j * in_dim + f], v, ir0);
    iz0 = fmaf(Wih[(j + H) * in_dim + f], v, iz0);
    in0 = fmaf(Wih[(j + 2 * H) * in_dim + f], v, in0);
    ir1 = fmaf(Wih[(j + 1) * in_dim + f], v, ir1);
    iz1 = fmaf(Wih[(j + 1 + H) * in_dim + f], v, iz1);
    in1 = fmaf(Wih[(j + 1 + 2 * H) * in_dim + f], v, in1);
  }
  float hr0 = bhh[j],     hz0 = bhh[j + H],     hn0 = bhh[j + 2 * H];
  float hr1 = bhh[j + 1], hz1 = bhh[j + 1 + H], hn1 = bhh[j + 1 + 2 * H];
  #pragma unroll 4
  for (int k = 0; k < H; ++k) {
    float v = hT[k * B + b];
    hr0 = fmaf(Whh[j * H + k], v, hr0);
    hz0 = fmaf(Whh[(j + H) * H + k], v, hz0);
    hn0 = fmaf(Whh[(j + 2 * H) * H + k], v, hn0);
    hr1 = fmaf(Whh[(j + 1) * H + k], v, hr1);
    hz1 = fmaf(Whh[(j + 1 + H) * H + k], v, hz1);
    hn1 = fmaf(Whh[(j + 1 + 2 * H) * H + k], v, hn1);
  }
  {
    float r = sigmoidf_(ir0 + hr0);
    float zg = sigmoidf_(iz0 + hz0);
    float n = tanhf(in0 + r * hn0);
    float hp = hT[j * B + b];
    h_outT[j * B + b] = (1.0f - zg) * n + zg * hp;
  }
  {
    float r = sigmoidf_(ir1 + hr1);
    float zg = sigmoidf_(iz1 + hz1);
    float n = tanhf(in1 + r * hn1);
    float hp = hT[(j + 1) * B + b];
    h_outT[(j + 1) * B + b] = (1.0f - zg) * n + zg * hp;
  }
}

// out[n][b] = act( W[n,:] . concat(in1,in2)[:, b] + bias[n] ); 2 n per block
__global__ __launch_bounds__(256) void k_mlp(const float* __restrict__ in1T, int K1,
                                             const float* __restrict__ in2T, int K2,
                                             const float* __restrict__ W,
                                             const float* __restrict__ bias,
                                             float* __restrict__ outT, int relu) {
  const int b = threadIdx.x;
  const int n = blockIdx.x * 2;
  const int K = K1 + K2;
  const float* w0 = W + (size_t)n * K;
  const float* w1 = W + (size_t)(n + 1) * K;
  float a0 = bias[n], a1 = bias[n + 1];
  #pragma unroll 4
  for (int k = 0; k < K1; ++k) {
    float v = in1T[k * B + b];
    a0 = fmaf(w0[k], v, a0);
    a1 = fmaf(w1[k], v, a1);
  }
  for (int k = 0; k < K2; ++k) {
    float v = in2T[k * B + b];
    a0 = fmaf(w0[K1 + k], v, a0);
    a1 = fmaf(w1[K1 + k], v, a1);
  }
  if (relu) { a0 = fmaxf(a0, 0.0f); a1 = fmaxf(a1, 0.0f); }
  outT[n * B + b] = a0;
  outT[(n + 1) * B + b] = a1;
}

// z head: z0 = loc + scale*eps; accumulates -log(scale) into kld
__global__ __launch_bounds__(256) void k_zhead(const float* __restrict__ h2T,
                                               const float* __restrict__ zlocW,
                                               const float* __restrict__ zlocb,
                                               const float* __restrict__ zscaleW,
                                               const float* __restrict__ zscaleb,
                                               const float* __restrict__ eps_t,
                                               float* __restrict__ zT,
                                               float* __restrict__ kld_acc) {
  const int b = threadIdx.x;
  const int z = blockIdx.x;  // 16
  const float* wl = zlocW + z * D;
  const float* ws = zscaleW + z * D;
  float al = zlocb[z], as = zscaleb[z];
  #pragma unroll 4
  for (int k = 0; k < D; ++k) {
    float v = h2T[k * B + b];
    al = fmaf(wl[k], v, al);
    as = fmaf(ws[k], v, as);
  }
  float scale = softplusf_(as) + 1e-6f;
  float ez = eps_t[b * Z + z];
  zT[z * B + b] = al + scale * ez;
  waveReduceAtomicAdd(kld_acc, -logf(scale), threadIdx.x);
}

// 20 planar flows, in-place on zT; accumulates -logdet into kld
__global__ __launch_bounds__(256) void k_flows(float* __restrict__ zT,
                                               const float* __restrict__ pu,
                                               const float* __restrict__ pw,
                                               const float* __restrict__ pb,
                                               float* __restrict__ kld_acc) {
  const int b = threadIdx.x;
  float zv[Z];
  #pragma unroll
  for (int i = 0; i < Z; ++i) zv[i] = zT[i * B + b];
  float ld = 0.0f;
  for (int f = 0; f < NF; ++f) {
    const float* w = pw + f * Z;
    const float* u = pu + f * Z;
    float wn2 = 0.0f, wu = 0.0f;
    #pragma unroll
    for (int i = 0; i < Z; ++i) { wn2 = fmaf(w[i], w[i], wn2); wu = fmaf(w[i], u[i], wu); }
    float coef = (softplusf_(wu) - 1.0f - wu) / wn2;
    float a_in = pb[f];
    #pragma unroll
    for (int i = 0; i < Z; ++i) a_in = fmaf(zv[i], w[i], a_in);
    float a = tanhf(a_in);
    float uw = 0.0f;
    #pragma unroll
    for (int i = 0; i < Z; ++i) {
      float uh = fmaf(coef, w[i], u[i]);
      uw = fmaf(uh, w[i], uw);
      zv[i] = fmaf(uh, a, zv[i]);
    }
    ld += logf(fabsf(1.0f + (1.0f - a * a) * uw) + 1e-12f);
  }
  #pragma unroll
  for (int i = 0; i < Z; ++i) zT[i * B + b] = zv[i];
  waveReduceAtomicAdd(kld_acc, -ld, threadIdx.x);
}

// y head: writes y_loc into d_out ([B,L,F] layout) and accumulates recon
__global__ __launch_bounds__(256) void k_yhead(const float* __restrict__ g2T,
                                               const float* __restrict__ xlocW,
                                               const float* __restrict__ xlocb,
                                               const float* __restrict__ xscaleW,
                                               const float* __restrict__ xscaleb,
                                               const float* __restrict__ xT_t,
                                               float* __restrict__ out_yloc, int t,
                                               float* __restrict__ recon_acc) {
  const int b = threadIdx.x;
  const int f = blockIdx.x;  // 38
  const float* wl = xlocW + f * D;
  const float* ws = xscaleW + f * D;
  float al = xlocb[f], as = xscaleb[f];
  #pragma unroll 4
  for (int k = 0; k < D; ++k) {
    float v = g2T[k * B + b];
    al = fmaf(wl[k], v, al);
    as = fmaf(ws[k], v, as);
  }
  float scale = softplusf_(as) + 1e-6f;
  out_yloc[((size_t)b * L + t) * F + f] = al;
  float xv = xT_t[f * B + b];
  float d = (xv - al) / scale;
  float nlp = 0.5f * d * d + logf(scale) + 0.5f * LOG2PI_F;  // = -log_prob
  waveReduceAtomicAdd(recon_acc, nlp, threadIdx.x);
}

__global__ void k_finalize(const float* __restrict__ acc, float* __restrict__ out) {
  out[(size_t)B * L * F] = acc[1];      // recon
  out[(size_t)B * L * F + 1] = acc[0];  // kld
}

}  // namespace

extern "C" void kernel_launch(void* const* d_in, const int* in_sizes, int n_in,
                              void* d_out, int out_size, void* d_ws, size_t ws_size,
                              hipStream_t stream) {
  const float* x        = (const float*)d_in[0];
  const float* phi_Wih  = (const float*)d_in[1];
  const float* phi_Whh  = (const float*)d_in[2];
  const float* phi_bih  = (const float*)d_in[3];
  const float* phi_bhh  = (const float*)d_in[4];
  const float* phi_W1   = (const float*)d_in[5];
  const float* phi_b1   = (const float*)d_in[6];
  const float* phi_W2   = (const float*)d_in[7];
  const float* phi_b2   = (const float*)d_in[8];
  const float* zloc_W   = (const float*)d_in[9];
  const float* zloc_b   = (const float*)d_in[10];
  const float* zscale_W = (const float*)d_in[11];
  const float* zscale_b = (const float*)d_in[12];
  const float* pu       = (const float*)d_in[13];
  const float* pw       = (const float*)d_in[14];
  const float* pb       = (const float*)d_in[15];
  const float* th_Wih   = (const float*)d_in[16];
  const float* th_Whh   = (const float*)d_in[17];
  const float* th_bih   = (const float*)d_in[18];
  const float* th_bhh   = (const float*)d_in[19];
  const float* th_W1    = (const float*)d_in[20];
  const float* th_b1    = (const float*)d_in[21];
  const float* th_W2    = (const float*)d_in[22];
  const float* th_b2    = (const float*)d_in[23];
  const float* xloc_W   = (const float*)d_in[24];
  const float* xloc_b   = (const float*)d_in[25];
  const float* xscale_W = (const float*)d_in[26];
  const float* xscale_b = (const float*)d_in[27];

  float* out = (float*)d_out;
  float* ws = (float*)d_ws;

  // workspace layout (floats)
  float* acc   = ws;                    // [0]=kld, [1]=recon
  float* eps_z = ws + 64;               // L*B*Z
  float* xT    = eps_z + LBZ;           // L*F*B
  float* hphi0 = xT + (size_t)L * F * B;
  float* hphi1 = hphi0 + H * B;
  float* hth0  = hphi1 + H * B;
  float* hth1  = hth0 + H * B;
  float* zT    = hth1 + H * B;          // Z*B
  float* h1T   = zT + Z * B;            // D*B
  float* h2T   = h1T + D * B;           // D*B

  // zero accumulators + carries (h states + z) — contiguous region
  hipMemsetAsync(acc, 0, 2 * sizeof(float), stream);
  hipMemsetAsync(hphi0, 0, (size_t)(4 * H * B + Z * B) * sizeof(float), stream);

  // JAX PRNG: key(42)=(0,42); split -> kz, kp
  uint32_t a0, a1, b0, b1;
  threefry2x32_(0u, 42u, 0u, 2u, a0, a1);
  threefry2x32_(0u, 42u, 1u, 3u, b0, b1);
  const uint32_t kz0 = a0, kz1 = b0, kp0 = a1, kp1 = b1;

  k_transpose_x<<<(B * L * F) / 256, 256, 0, stream>>>(x, xT);
  k_noise<<<HALF / 256, 256, 0, stream>>>(eps_z, acc, kz0, kz1, kp0, kp1);

  for (int t = 0; t < L; ++t) {
    float* hphi_c = (t & 1) ? hphi1 : hphi0;
    float* hphi_n = (t & 1) ? hphi0 : hphi1;
    float* hth_c  = (t & 1) ? hth1 : hth0;
    float* hth_n  = (t & 1) ? hth0 : hth1;
    const float* xT_t = xT + (size_t)t * F * B;

    k_gru<<<H / 2, 256, 0, stream>>>(xT_t, F, hphi_c, phi_Wih, phi_Whh,
                                     phi_bih, phi_bhh, hphi_n);
    k_mlp<<<D / 2, 256, 0, stream>>>(hphi_n, H, zT, Z, phi_W1, phi_b1, h1T, 1);
    k_mlp<<<D / 2, 256, 0, stream>>>(h1T, D, nullptr, 0, phi_W2, phi_b2, h2T, 0);
    k_zhead<<<Z, 256, 0, stream>>>(h2T, zloc_W, zloc_b, zscale_W, zscale_b,
                                   eps_z + (size_t)t * B * Z, zT, acc);
    k_flows<<<1, 256, 0, stream>>>(zT, pu, pw, pb, acc);
    k_gru<<<H / 2, 256, 0, stream>>>(zT, Z, hth_c, th_Wih, th_Whh,
                                     th_bih, th_bhh, hth_n);
    k_mlp<<<D / 2, 256, 0, stream>>>(hth_n, D, nullptr, 0, th_W1, th_b1, h1T, 1);
    k_mlp<<<D / 2, 256, 0, stream>>>(h1T, D, nullptr, 0, th_W2, th_b2, h2T, 0);
    k_yhead<<<F, 256, 0, stream>>>(h2T, xloc_W, xloc_b, xscale_W, xscale_b,
                                   xT_t, out, t, acc + 1);
  }
  k_finalize<<<1, 1, 0, stream>>>(acc, out);
}

// Round 2
// 39097.733 us; speedup vs baseline: 2.2823x; 2.2823x over previous
//
#include <hip/hip_runtime.h>
#include <stdint.h>
#include <math.h>

namespace {

constexpr int B = 256, L = 256, F = 38, H = 512, D = 512, Z = 16, NF = 20;
constexpr float LOG2PI_F = 1.8378770664093453f;
constexpr int LBZ = L * B * Z;      // 1048576
constexpr int HALF = LBZ / 2;       // 524288
constexpr int HB = H * B;           // 131072
constexpr int DB = D * B;           // 131072
constexpr int ZB = Z * B;           // 4096
constexpr int LFB = L * F * B;      // 2490368
constexpr int TC = 32;              // tail chunk (timesteps)

// ---------------- math helpers ----------------

__device__ __forceinline__ float sigmoidf_(float x) {
  return 1.0f / (1.0f + expf(-x));
}
__device__ __forceinline__ float softplusf_(float x) {
  return fmaxf(x, 0.0f) + log1pf(expf(-fabsf(x)));
}

__device__ __forceinline__ void waveReduceAtomicAdd(float* dst, float v, int tid) {
  #pragma unroll
  for (int off = 32; off > 0; off >>= 1) v += __shfl_down(v, off, 64);
  if ((tid & 63) == 0) atomicAdd(dst, v);
}

// ---------------- threefry2x32 (JAX-compatible) ----------------

__host__ __device__ inline uint32_t rotl32_(uint32_t x, int d) {
  return (x << d) | (x >> (32 - d));
}

__host__ __device__ inline void threefry2x32_(uint32_t k0, uint32_t k1,
                                              uint32_t x0, uint32_t x1,
                                              uint32_t& o0, uint32_t& o1) {
  const uint32_t ks2 = k0 ^ k1 ^ 0x1BD11BDAu;
  uint32_t v0 = x0 + k0;
  uint32_t v1 = x1 + k1;
#define TF_RND(r) { v0 += v1; v1 = rotl32_(v1, r); v1 ^= v0; }
  TF_RND(13) TF_RND(15) TF_RND(26) TF_RND(6)
  v0 += k1;  v1 += ks2 + 1u;
  TF_RND(17) TF_RND(29) TF_RND(16) TF_RND(24)
  v0 += ks2; v1 += k0 + 2u;
  TF_RND(13) TF_RND(15) TF_RND(26) TF_RND(6)
  v0 += k0;  v1 += k1 + 3u;
  TF_RND(17) TF_RND(29) TF_RND(16) TF_RND(24)
  v0 += k1;  v1 += ks2 + 4u;
  TF_RND(13) TF_RND(15) TF_RND(26) TF_RND(6)
  v0 += ks2; v1 += k0 + 5u;
#undef TF_RND
  o0 = v0; o1 = v1;
}

__device__ __forceinline__ float erfinv_f_(float x) {
  float w = -log1pf(-x * x);
  float p;
  if (w < 5.0f) {
    w -= 2.5f;
    p = 2.81022636e-08f;
    p = fmaf(p, w, 3.43273939e-07f);
    p = fmaf(p, w, -3.5233877e-06f);
    p = fmaf(p, w, -4.39150654e-06f);
    p = fmaf(p, w, 0.00021858087f);
    p = fmaf(p, w, -0.00125372503f);
    p = fmaf(p, w, -0.00417768164f);
    p = fmaf(p, w, 0.246640727f);
    p = fmaf(p, w, 1.50140941f);
  } else {
    w = sqrtf(w) - 3.0f;
    p = -0.000200214257f;
    p = fmaf(p, w, 0.000100950558f);
    p = fmaf(p, w, 0.00134934322f);
    p = fmaf(p, w, -0.00367342844f);
    p = fmaf(p, w, 0.00573950773f);
    p = fmaf(p, w, -0.0076224613f);
    p = fmaf(p, w, 0.00943887047f);
    p = fmaf(p, w, 1.00167406f);
    p = fmaf(p, w, 2.83297682f);
  }
  return p * x;
}

__device__ __forceinline__ float bits_to_normal_(uint32_t bits) {
  uint32_t m = (bits >> 9) | 0x3f800000u;
  float f = __uint_as_float(m) - 1.0f;
  float u = f * 2.0f + (-0.99999994f);
  u = fmaxf(-0.99999994f, u);
  return 1.41421356f * erfinv_f_(u);
}

// planar flows for one batch column (per-lane), returns logdet; zv updated in place
__device__ __forceinline__ float flows_dev(float zv[Z], const float* __restrict__ pu,
                                           const float* __restrict__ pw,
                                           const float* __restrict__ pb) {
  float ld = 0.0f;
  for (int f = 0; f < NF; ++f) {
    const float* w = pw + f * Z;
    const float* u = pu + f * Z;
    float wn2 = 0.0f, wu = 0.0f;
    #pragma unroll
    for (int i = 0; i < Z; ++i) { wn2 = fmaf(w[i], w[i], wn2); wu = fmaf(w[i], u[i], wu); }
    float coef = (softplusf_(wu) - 1.0f - wu) / wn2;
    float a_in = pb[f];
    #pragma unroll
    for (int i = 0; i < Z; ++i) a_in = fmaf(zv[i], w[i], a_in);
    float a = tanhf(a_in);
    float uw = 0.0f;
    #pragma unroll
    for (int i = 0; i < Z; ++i) {
      float uh = fmaf(coef, w[i], u[i]);
      uw = fmaf(uh, w[i], uw);
      zv[i] = fmaf(uh, a, zv[i]);
    }
    ld += logf(fabsf(1.0f + (1.0f - a * a) * uw) + 1e-12f);
  }
  return ld;
}

// ---------------- small utility kernels ----------------

__global__ __launch_bounds__(256) void k_transpose_x(const float* __restrict__ x,
                                                     float* __restrict__ xT) {
  int idx = blockIdx.x * blockDim.x + threadIdx.x;  // over B*L*F
  int f = idx % F;
  int t = (idx / F) % L;
  int b = idx / (F * L);
  xT[(t * F + f) * B + b] = x[idx];
}

__global__ __launch_bounds__(256) void k_noise(float* __restrict__ eps_z,
                                               float* __restrict__ kld_acc,
                                               uint32_t kz0, uint32_t kz1,
                                               uint32_t kp0, uint32_t kp1) {
  int i = blockIdx.x * blockDim.x + threadIdx.x;  // [0, HALF)
  uint32_t a0, a1, b0, b1;
  threefry2x32_(kz0, kz1, (uint32_t)i, (uint32_t)(i + HALF), a0, a1);
  float ez0 = bits_to_normal_(a0);
  float ez1 = bits_to_normal_(a1);
  eps_z[i] = ez0;
  eps_z[i + HALF] = ez1;
  threefry2x32_(kp0, kp1, (uint32_t)i, (uint32_t)(i + HALF), b0, b1);
  float ep0 = bits_to_normal_(b0);
  float ep1 = bits_to_normal_(b1);
  float local = -0.5f * (ez0 * ez0 + ez1 * ez1) + 0.5f * (ep0 * ep0 + ep1 * ep1);
  waveReduceAtomicAdd(kld_acc, local, threadIdx.x);
}

__global__ void k_finalize(const float* __restrict__ acc, float* __restrict__ out) {
  out[(size_t)B * L * F] = acc[1];      // recon
  out[(size_t)B * L * F + 1] = acc[0];  // kld
}

// ---------------- wave-row GRU kernel ----------------
// Block: 4 waves x 64 lanes. Lanes = batch columns (b0+lane). Block owns 8
// output rows j0..j0+7. K split: wave0 does x-part (K1) + w0h h-rows; waves
// 1..3 split the remaining h-rows evenly. Weight fetches are wave-uniform ->
// scalar loads. Cross-wave reduce through LDS, fused GRU gate epilogue.
// THETA variant: wave0 runs the planar flows in registers first (z-input),
// block column 0 publishes z_t and the -logdet kld term.
template<bool THETA>
__global__ __launch_bounds__(256) void k_gru(
    const float* __restrict__ xin,   // THETA: z0T [Z][B]; else xT_t [K1][B]
    const float* __restrict__ hT,    // [H][B] previous hidden
    const float* __restrict__ Wih,   // [3H][K1]
    const float* __restrict__ Whh,   // [3H][H]
    const float* __restrict__ bih, const float* __restrict__ bhh,
    int K1, int w0h,
    float* __restrict__ hout,        // [H][B]
    float* __restrict__ zT_out,
    const float* __restrict__ pu, const float* __restrict__ pw,
    const float* __restrict__ pb,
    float* __restrict__ kld_acc) {
  const int tid = threadIdx.x;
  const int lane = tid & 63;
  const int wv = __builtin_amdgcn_readfirstlane(tid >> 6);
  const int j0 = blockIdx.x * 8;
  const int b0 = blockIdx.y * 64;
  const int b = b0 + lane;

  float accR[8], accZ[8], accNX[8], accNH[8];
  #pragma unroll
  for (int r = 0; r < 8; ++r) { accR[r] = 0.f; accZ[r] = 0.f; accNX[r] = 0.f; accNH[r] = 0.f; }

  float zv[Z];
  float ld = 0.0f;

  if (wv == 0) {
    const float* wr = Wih + (size_t)(0 * H + j0) * K1;
    const float* wz = Wih + (size_t)(1 * H + j0) * K1;
    const float* wn = Wih + (size_t)(2 * H + j0) * K1;
    if (THETA) {
      #pragma unroll
      for (int i = 0; i < Z; ++i) zv[i] = xin[i * B + b];
      ld = flows_dev(zv, pu, pw, pb);
      #pragma unroll
      for (int k = 0; k < Z; ++k) {
        float a = zv[k];
        #pragma unroll
        for (int r = 0; r < 8; ++r) {
          accR[r]  = fmaf(wr[r * K1 + k], a, accR[r]);
          accZ[r]  = fmaf(wz[r * K1 + k], a, accZ[r]);
          accNX[r] = fmaf(wn[r * K1 + k], a, accNX[r]);
        }
      }
    } else {
      for (int k = 0; k < K1; ++k) {
        float a = xin[k * B + b];
        #pragma unroll
        for (int r = 0; r < 8; ++r) {
          accR[r]  = fmaf(wr[r * K1 + k], a, accR[r]);
          accZ[r]  = fmaf(wz[r * K1 + k], a, accZ[r]);
          accNX[r] = fmaf(wn[r * K1 + k], a, accNX[r]);
        }
      }
    }
  }

  // h-part
  int hlo, hhi;
  {
    int rest = (H - w0h) / 3;
    if (wv == 0) { hlo = 0; hhi = w0h; }
    else { hlo = w0h + (wv - 1) * rest; hhi = hlo + rest; }
  }
  {
    const float* vr = Whh + (size_t)(0 * H + j0) * H;
    const float* vz = Whh + (size_t)(1 * H + j0) * H;
    const float* vn = Whh + (size_t)(2 * H + j0) * H;
    #pragma unroll 2
    for (int k = hlo; k < hhi; ++k) {
      float a = hT[k * B + b];
      #pragma unroll
      for (int r = 0; r < 8; ++r) {
        accR[r]  = fmaf(vr[r * H + k], a, accR[r]);
        accZ[r]  = fmaf(vz[r * H + k], a, accZ[r]);
        accNH[r] = fmaf(vn[r * H + k], a, accNH[r]);
      }
    }
  }

  __shared__ float red[4][4][8][64];  // [wave][group][row][lane] = 32 KB
  #pragma unroll
  for (int r = 0; r < 8; ++r) {
    red[wv][0][r][lane] = accR[r];
    red[wv][1][r][lane] = accZ[r];
    red[wv][2][r][lane] = accNX[r];
    red[wv][3][r][lane] = accNH[r];
  }

  if (THETA) {
    if (wv == 0 && blockIdx.x == 0) {
      #pragma unroll
      for (int i = 0; i < Z; ++i) zT_out[i * B + b] = zv[i];
      waveReduceAtomicAdd(kld_acc, -ld, lane);
    }
  }

  __syncthreads();

  #pragma unroll
  for (int it = tid; it < 512; it += 256) {
    int r = it >> 6, l = it & 63;
    float sR = 0.f, sZ = 0.f, sNX = 0.f, sNH = 0.f;
    #pragma unroll
    for (int w = 0; w < 4; ++w) {
      sR  += red[w][0][r][l];
      sZ  += red[w][1][r][l];
      sNX += red[w][2][r][l];
      sNH += red[w][3][r][l];
    }
    int j = j0 + r;
    int bb = b0 + l;
    float rg = sigmoidf_(sR + bih[j] + bhh[j]);
    float zg = sigmoidf_(sZ + bih[H + j] + bhh[H + j]);
    float ng = tanhf(sNX + bih[2 * H + j] + rg * (sNH + bhh[2 * H + j]));
    float hp = hT[(size_t)j * B + bb];
    hout[(size_t)j * B + bb] = (1.0f - zg) * ng + zg * hp;
  }
}

// ---------------- wave-row linear kernel ----------------
// out[r][b] = act(W[r,:] . concat(A1,A2)[:,b] + bias[r]); rows 8/block,
// K split 4 ways across waves, LDS reduce. grid.z batches over timesteps.
__global__ __launch_bounds__(256) void k_lin(
    const float* __restrict__ A1, int K1, long sA1,
    const float* __restrict__ A2, int K2,
    const float* __restrict__ W, const float* __restrict__ bias,
    float* __restrict__ outp, long sOut, int relu) {
  const int tid = threadIdx.x;
  const int lane = tid & 63;
  const int wv = __builtin_amdgcn_readfirstlane(tid >> 6);
  const int r0 = blockIdx.x * 8;
  const int b0 = blockIdx.y * 64;
  const int b = b0 + lane;
  const int Kv = K1 + K2;
  const float* A1p = A1 + (size_t)blockIdx.z * sA1;
  float* outpp = outp + (size_t)blockIdx.z * sOut;
  const int klo = wv * (Kv >> 2);
  const int khi = klo + (Kv >> 2);

  float acc[8];
  #pragma unroll
  for (int r = 0; r < 8; ++r) acc[r] = 0.f;

  const float* wbase = W + (size_t)r0 * Kv;
  {
    int lo = klo, hi = khi < K1 ? khi : K1;
    #pragma unroll 2
    for (int k = lo; k < hi; ++k) {
      float a = A1p[(size_t)k * B + b];
      #pragma unroll
      for (int r = 0; r < 8; ++r) acc[r] = fmaf(wbase[(size_t)r * Kv + k], a, acc[r]);
    }
  }
  {
    int lo = klo > K1 ? klo : K1, hi = khi;
    for (int k = lo; k < hi; ++k) {
      float a = A2[(size_t)(k - K1) * B + b];
      #pragma unroll
      for (int r = 0; r < 8; ++r) acc[r] = fmaf(wbase[(size_t)r * Kv + k], a, acc[r]);
    }
  }

  __shared__ float red[4][8][64];  // 8 KB
  #pragma unroll
  for (int r = 0; r < 8; ++r) red[wv][r][lane] = acc[r];
  __syncthreads();

  #pragma unroll
  for (int it = tid; it < 512; it += 256) {
    int r = it >> 6, l = it & 63;
    float s = red[0][r][l] + red[1][r][l] + red[2][r][l] + red[3][r][l] + bias[r0 + r];
    if (relu) s = fmaxf(s, 0.f);
    outpp[(size_t)(r0 + r) * B + b0 + l] = s;
  }
}

// ---------------- z head ----------------
// 4 z-values per block, each with (loc,scale) row pair. K=512 split 4.
__global__ __launch_bounds__(256) void k_zhead(
    const float* __restrict__ h2T,
    const float* __restrict__ zlocW, const float* __restrict__ zlocb,
    const float* __restrict__ zscaleW, const float* __restrict__ zscaleb,
    const float* __restrict__ eps_t,   // [B][Z]
    float* __restrict__ z0T, float* __restrict__ kld_acc) {
  const int tid = threadIdx.x;
  const int lane = tid & 63;
  const int wv = __builtin_amdgcn_readfirstlane(tid >> 6);
  const int z0q = blockIdx.x * 4;
  const int b0 = blockIdx.y * 64;
  const int b = b0 + lane;
  const int klo = wv * (D >> 2), khi = klo + (D >> 2);

  const float* wp[8];
  #pragma unroll
  for (int i = 0; i < 8; ++i) {
    int zz = z0q + (i >> 1);
    wp[i] = ((i & 1) ? zscaleW : zlocW) + (size_t)zz * D;
  }
  float acc[8];
  #pragma unroll
  for (int i = 0; i < 8; ++i) acc[i] = 0.f;
  #pragma unroll 2
  for (int k = klo; k < khi; ++k) {
    float a = h2T[(size_t)k * B + b];
    #pragma unroll
    for (int i = 0; i < 8; ++i) acc[i] = fmaf(wp[i][k], a, acc[i]);
  }

  __shared__ float red[4][8][64];
  #pragma unroll
  for (int i = 0; i < 8; ++i) red[wv][i][lane] = acc[i];
  __syncthreads();

  int zi = tid >> 6, l = tid & 63;
  int zz = z0q + zi;
  int bb = b0 + l;
  float sl = red[0][2 * zi][l] + red[1][2 * zi][l] + red[2][2 * zi][l] + red[3][2 * zi][l]
             + zlocb[zz];
  float ss = red[0][2 * zi + 1][l] + red[1][2 * zi + 1][l] + red[2][2 * zi + 1][l]
             + red[3][2 * zi + 1][l] + zscaleb[zz];
  float scale = softplusf_(ss) + 1e-6f;
  float ez = eps_t[bb * Z + zz];
  z0T[zz * B + bb] = sl + scale * ez;
  waveReduceAtomicAdd(kld_acc, -logf(scale), tid);
}

// ---------------- y head ----------------
// 4 features per block ((loc,scale) pairs), grid.z batches timesteps.
__global__ __launch_bounds__(256) void k_yhead(
    const float* __restrict__ g2base, long sG2, int t_base,
    const float* __restrict__ xlocW, const float* __restrict__ xlocb,
    const float* __restrict__ xscaleW, const float* __restrict__ xscaleb,
    const float* __restrict__ xT,    // [L][F][B]
    float* __restrict__ out_yloc, float* __restrict__ recon_acc) {
  const int tid = threadIdx.x;
  const int lane = tid & 63;
  const int wv = __builtin_amdgcn_readfirstlane(tid >> 6);
  const int t = t_base + blockIdx.z;
  const float* g2T = g2base + (size_t)blockIdx.z * sG2;
  const int f0 = blockIdx.x * 4;
  const int b0 = blockIdx.y * 64;
  const int b = b0 + lane;
  const int klo = wv * (D >> 2), khi = klo + (D >> 2);

  const float* wp[8];
  #pragma unroll
  for (int i = 0; i < 8; ++i) {
    int ff = f0 + (i >> 1);
    int fc = ff < F ? ff : 0;
    wp[i] = ((i & 1) ? xscaleW : xlocW) + (size_t)fc * D;
  }
  float acc[8];
  #pragma unroll
  for (int i = 0; i < 8; ++i) acc[i] = 0.f;
  #pragma unroll 2
  for (int k = klo; k < khi; ++k) {
    float a = g2T[(size_t)k * B + b];
    #pragma unroll
    for (int i = 0; i < 8; ++i) acc[i] = fmaf(wp[i][k], a, acc[i]);
  }

  __shared__ float red[4][8][64];
  #pragma unroll
  for (int i = 0; i < 8; ++i) red[wv][i][lane] = acc[i];
  __syncthreads();

  int fi = tid >> 6, l = tid & 63;
  int ff = f0 + fi;
  int bb = b0 + l;
  float nl = 0.0f;
  if (ff < F) {
    float loc = red[0][2 * fi][l] + red[1][2 * fi][l] + red[2][2 * fi][l] + red[3][2 * fi][l]
                + xlocb[ff];
    float sp = red[0][2 * fi + 1][l] + red[1][2 * fi + 1][l] + red[2][2 * fi + 1][l]
               + red[3][2 * fi + 1][l] + xscaleb[ff];
    float scale = softplusf_(sp) + 1e-6f;
    out_yloc[((size_t)bb * L + t) * F + ff] = loc;
    float xv = xT[((size_t)t * F + ff) * B + bb];
    float d = (xv - loc) / scale;
    nl = 0.5f * d * d + logf(scale) + 0.5f * LOG2PI_F;
  }
  waveReduceAtomicAdd(recon_acc, nl, tid);
}

}  // namespace

extern "C" void kernel_launch(void* const* d_in, const int* in_sizes, int n_in,
                              void* d_out, int out_size, void* d_ws, size_t ws_size,
                              hipStream_t stream) {
  const float* x        = (const float*)d_in[0];
  const float* phi_Wih  = (const float*)d_in[1];
  const float* phi_Whh  = (const float*)d_in[2];
  const float* phi_bih  = (const float*)d_in[3];
  const float* phi_bhh  = (const float*)d_in[4];
  const float* phi_W1   = (const float*)d_in[5];
  const float* phi_b1   = (const float*)d_in[6];
  const float* phi_W2   = (const float*)d_in[7];
  const float* phi_b2   = (const float*)d_in[8];
  const float* zloc_W   = (const float*)d_in[9];
  const float* zloc_b   = (const float*)d_in[10];
  const float* zscale_W = (const float*)d_in[11];
  const float* zscale_b = (const float*)d_in[12];
  const float* pu       = (const float*)d_in[13];
  const float* pw       = (const float*)d_in[14];
  const float* pb       = (const float*)d_in[15];
  const float* th_Wih   = (const float*)d_in[16];
  const float* th_Whh   = (const float*)d_in[17];
  const float* th_bih   = (const float*)d_in[18];
  const float* th_bhh   = (const float*)d_in[19];
  const float* th_W1    = (const float*)d_in[20];
  const float* th_b1    = (const float*)d_in[21];
  const float* th_W2    = (const float*)d_in[22];
  const float* th_b2    = (const float*)d_in[23];
  const float* xloc_W   = (const float*)d_in[24];
  const float* xloc_b   = (const float*)d_in[25];
  const float* xscale_W = (const float*)d_in[26];
  const float* xscale_b = (const float*)d_in[27];

  float* out = (float*)d_out;
  float* ws = (float*)d_ws;

  // common workspace layout (floats)
  float* acc   = ws;                 // [0]=kld, [1]=recon
  float* eps_z = ws + 64;            // LBZ
  float* xT    = eps_z + LBZ;        // LFB
  float* hphi0 = xT + LFB;           // HB
  float* hphi1 = hphi0 + HB;         // HB
  float* zT    = hphi1 + HB;         // ZB
  float* z0T   = zT + ZB;            // ZB
  float* h1T   = z0T + ZB;           // DB
  float* h2T   = h1T + DB;           // DB
  float* tailbase = h2T + DB;

  // path A: store th_h for all t, defer theta-MLP/y-head to batched tail
  size_t floatsA = (size_t)(tailbase - ws) + (size_t)(L + 1) * HB + 2 * (size_t)TC * DB;
  bool pathA = ws_size >= floatsA * sizeof(float);

  float* th_all = tailbase;                        // (L+1)*HB (path A)
  float* g1_c   = th_all + (size_t)(L + 1) * HB;   // TC*DB
  float* g2_c   = g1_c + (size_t)TC * DB;          // TC*DB
  float* hth0   = tailbase;                        // path B ping-pong
  float* hth1   = tailbase + HB;

  hipMemsetAsync(acc, 0, 2 * sizeof(float), stream);
  hipMemsetAsync(hphi0, 0, (size_t)HB * sizeof(float), stream);
  hipMemsetAsync(zT, 0, (size_t)ZB * sizeof(float), stream);
  if (pathA) hipMemsetAsync(th_all, 0, (size_t)HB * sizeof(float), stream);
  else       hipMemsetAsync(hth0, 0, (size_t)HB * sizeof(float), stream);

  // JAX PRNG: key(42)=(0,42); split -> kz, kp
  uint32_t a0, a1, b0, b1;
  threefry2x32_(0u, 42u, 0u, 2u, a0, a1);
  threefry2x32_(0u, 42u, 1u, 3u, b0, b1);
  const uint32_t kz0 = a0, kz1 = b0, kp0 = a1, kp1 = b1;

  k_transpose_x<<<(B * L * F) / 256, 256, 0, stream>>>(x, xT);
  k_noise<<<HALF / 256, 256, 0, stream>>>(eps_z, acc, kz0, kz1, kp0, kp1);

  const dim3 gGru(H / 8, B / 64, 1);
  const dim3 gLin(D / 8, B / 64, 1);
  const dim3 gZ(Z / 4, B / 64, 1);
  const dim3 gY((F + 3) / 4, B / 64, 1);

  for (int t = 0; t < L; ++t) {
    float* hphi_c = (t & 1) ? hphi1 : hphi0;
    float* hphi_n = (t & 1) ? hphi0 : hphi1;
    float* hth_c = pathA ? (th_all + (size_t)t * HB) : ((t & 1) ? hth1 : hth0);
    float* hth_n = pathA ? (th_all + (size_t)(t + 1) * HB) : ((t & 1) ? hth0 : hth1);
    const float* xT_t = xT + (size_t)t * F * B;

    // phi GRU: wave0 gets x-part(38) + 89 h-rows; others 141 each
    k_gru<false><<<gGru, 256, 0, stream>>>(xT_t, hphi_c, phi_Wih, phi_Whh,
                                           phi_bih, phi_bhh, F, 89, hphi_n,
                                           nullptr, nullptr, nullptr, nullptr, nullptr);
    // MLP1: concat(phi_h, z_prev) -> relu
    k_lin<<<gLin, 256, 0, stream>>>(hphi_n, H, 0, zT, Z, phi_W1, phi_b1, h1T, 0, 1);
    // MLP2
    k_lin<<<gLin, 256, 0, stream>>>(h1T, D, 0, nullptr, 0, phi_W2, phi_b2, h2T, 0, 0);
    // z head -> z0, kld(-log sigma)
    k_zhead<<<gZ, 256, 0, stream>>>(h2T, zloc_W, zloc_b, zscale_W, zscale_b,
                                    eps_z + (size_t)t * B * Z, z0T, acc);
    // theta GRU with fused flows: wave0 flows+z-part(16)+80 h-rows; others 144
    k_gru<true><<<gGru, 256, 0, stream>>>(z0T, hth_c, th_Wih, th_Whh,
                                          th_bih, th_bhh, Z, 80, hth_n,
                                          zT, pu, pw, pb, acc);

    if (!pathA) {
      k_lin<<<gLin, 256, 0, stream>>>(hth_n, H, 0, nullptr, 0, th_W1, th_b1, h1T, 0, 1);
      k_lin<<<gLin, 256, 0, stream>>>(h1T, D, 0, nullptr, 0, th_W2, th_b2, h2T, 0, 0);
      k_yhead<<<gY, 256, 0, stream>>>(h2T, 0, t, xloc_W, xloc_b, xscale_W, xscale_b,
                                      xT, out, acc + 1);
    }
  }

  if (pathA) {
    // deferred theta tail, chunked over timesteps
    for (int c = 0; c < L / TC; ++c) {
      const float* thh = th_all + (size_t)(c * TC + 1) * HB;
      dim3 g1(D / 8, B / 64, TC);
      k_lin<<<g1, 256, 0, stream>>>(thh, H, HB, nullptr, 0, th_W1, th_b1, g1_c, DB, 1);
      k_lin<<<g1, 256, 0, stream>>>(g1_c, D, DB, nullptr, 0, th_W2, th_b2, g2_c, DB, 0);
      dim3 gy((F + 3) / 4, B / 64, TC);
      k_yhead<<<gy, 256, 0, stream>>>(g2_c, DB, c * TC, xloc_W, xloc_b,
                                      xscale_W, xscale_b, xT, out, acc + 1);
    }
  }

  k_finalize<<<1, 1, 0, stream>>>(acc, out);
}